// Round 1
// baseline (130.600 us; speedup 1.0000x reference)
//
#include <hip/hip_runtime.h>
#include <stdint.h>

#define HH 2048
#define WW 2048
#define NPIX (HH*WW)
#define TS 64

// ---------------- Kernel A: fw = sum over 5 channels (u8), init minmax ----------------
__global__ __launch_bounds__(256) void fw_kernel(
    const float* __restrict__ target, uint8_t* __restrict__ fw,
    uint32_t* __restrict__ minmax)
{
    int i = blockIdx.x * 256 + threadIdx.x;   // quad index, grid sized exactly
    if (i == 0) { minmax[0] = 0x7F800000u; minmax[1] = 0u; }  // +inf, 0.0
    const float4* t4 = (const float4*)target;
    float4 a = t4[i];
    float4 b = t4[(NPIX/4) + i];
    float4 c = t4[2*(NPIX/4) + i];
    float4 d = t4[3*(NPIX/4) + i];
    float4 e = t4[4*(NPIX/4) + i];
    uchar4 o;
    o.x = (unsigned char)(a.x + b.x + c.x + d.x + e.x);
    o.y = (unsigned char)(a.y + b.y + c.y + d.y + e.y);
    o.z = (unsigned char)(a.z + b.z + c.z + d.z + e.z);
    o.w = (unsigned char)(a.w + b.w + c.w + d.w + e.w);
    ((uchar4*)fw)[i] = o;
}

// ---------------- Kernel B: contour + w = (fw+contour)^2, global min/max ----------------
// 64x64 tile per block, 256 threads. Bit-packed 72-row halo mask in LDS.
__global__ __launch_bounds__(256) void contour_kernel(
    const uint8_t* __restrict__ fw, const float* __restrict__ dk,
    float* __restrict__ wout, uint32_t* __restrict__ minmax)
{
    __shared__ uint32_t maskw[72][4];   // 72 halo rows x 3 used words (96 bits)
    __shared__ float inv_d2[40];        // d^2 -> 1/dist (only achievable slots written)

    const int t   = threadIdx.x;
    const int gx0 = blockIdx.x * TS;
    const int gy0 = blockIdx.y * TS;

    // Build inverse-distance table from the input kernel (redundant identical writes OK)
    if (t < 81) {
        int iy = t / 9, jx = t - (t / 9) * 9;
        int dy = iy - 4, dx = jx - 4;
        int d2 = dy * dy + dx * dx;
        if (d2 != 0)
            inv_d2[d2] = 1.0f / (dk[t] / (1.0f + 1e-10f) + 1e-10f);
    }

    // Build bit-packed halo mask: bit b of row hr = (fw[clamp(gy0-4+hr)][clamp(gx0-4+b)] > 0)
    for (int w = t; w < 216; w += 256) {
        int hr = w / 3, wc = w - hr * 3;
        int gy = gy0 - 4 + hr; gy = min(max(gy, 0), HH - 1);
        const uint8_t* rowp = fw + gy * WW;
        int base = gx0 - 4 + wc * 32;
        uint32_t bits = 0u;
        #pragma unroll
        for (int bi = 0; bi < 32; ++bi) {
            int gx = base + bi; gx = min(max(gx, 0), WW - 1);
            bits |= (rowp[gx] ? 1u : 0u) << bi;
        }
        maskw[hr][wc] = bits;
    }
    __syncthreads();

    const int tx   = t & 63;      // tile column
    const int tg   = t >> 6;      // wave id: rows tg*16 .. tg*16+15
    const int r0   = tg * 16;
    const int wsel = tx >> 5;
    const uint32_t sh = (uint32_t)(tx & 31);
    const int gx = gx0 + tx;

    // rolling 9-row window of 9-bit mask slices (bit k = dx offset k-4)
    uint32_t w9[9];
    #pragma unroll
    for (int k = 0; k < 9; ++k) {
        uint32_t lo = maskw[r0 + k][wsel];
        uint32_t hi = maskw[r0 + k][wsel + 1];
        w9[k] = (uint32_t)(((((uint64_t)hi) << 32) | lo) >> sh) & 0x1FFu;
    }

    float lmn = __int_as_float(0x7F800000);  // +inf
    float lmx = 0.0f;

    #pragma unroll
    for (int r = 0; r < 16; ++r) {
        const int gy = gy0 + r0 + r;
        uint32_t cbit = (w9[4] >> 4) & 1u;
        uint32_t cm = 0u - cbit;                  // 0 or all-ones
        uint32_t mind2 = 999u;
        #pragma unroll
        for (int dy = 0; dy < 9; ++dy) {
            uint32_t x = (w9[dy] ^ cm) & 0x1FFu;  // differ bits (center bit self-xor = 0)
            uint32_t rev = __builtin_bitreverse32(x) >> 23;      // 9-bit reversal: dx -> -dx
            uint32_t g = (((x | rev) >> 4) & 0x1Fu) | 0x100u;    // bit k = |dx|==k present; sentinel
            uint32_t mk = (uint32_t)__builtin_ctz(g);            // min |dx|, or 8 if none
            uint32_t d2 = mk * mk + (uint32_t)((dy - 4) * (dy - 4));
            mind2 = min(mind2, d2);
        }
        float contour = (mind2 <= 32u) ? inv_d2[mind2] : 0.0f;
        float fwv = (float)fw[gy * WW + gx];
        float wv = fwv + contour;
        wv = wv * wv;
        wout[gy * WW + gx] = wv;
        lmn = fminf(lmn, wv);
        lmx = fmaxf(lmx, wv);
        if (r < 15) {
            #pragma unroll
            for (int k = 0; k < 8; ++k) w9[k] = w9[k + 1];
            uint32_t lo = maskw[r0 + r + 9][wsel];
            uint32_t hi = maskw[r0 + r + 9][wsel + 1];
            w9[8] = (uint32_t)(((((uint64_t)hi) << 32) | lo) >> sh) & 0x1FFu;
        }
    }

    // wave reduce min/max, one atomic pair per wave (uint order valid for nonneg floats)
    #pragma unroll
    for (int off = 32; off > 0; off >>= 1) {
        lmn = fminf(lmn, __shfl_xor(lmn, off));
        lmx = fmaxf(lmx, __shfl_xor(lmx, off));
    }
    if (tx == 0) {
        atomicMin(minmax + 0, __float_as_uint(lmn));
        atomicMax(minmax + 1, __float_as_uint(lmx));
    }
}

// ---------------- Kernel C: normalize + mask ----------------
__global__ __launch_bounds__(256) void norm_kernel(
    const float* w, const uint8_t* __restrict__ fw,
    const uint32_t* __restrict__ minmax, float* out)
{
    int i = blockIdx.x * 256 + threadIdx.x;   // quad index, grid sized exactly
    float mn = __uint_as_float(minmax[0]);
    float mx = __uint_as_float(minmax[1]);
    float rden = 1.0f / (mx - mn + 1e-10f);
    float4 wv = ((const float4*)w)[i];
    uchar4 f = ((const uchar4*)fw)[i];
    float4 o;
    o.x = f.x ? (wv.x - mn) * rden : 0.0f;
    o.y = f.y ? (wv.y - mn) * rden : 0.0f;
    o.z = f.z ? (wv.z - mn) * rden : 0.0f;
    o.w = f.w ? (wv.w - mn) * rden : 0.0f;
    ((float4*)out)[i] = o;
}

extern "C" void kernel_launch(void* const* d_in, const int* in_sizes, int n_in,
                              void* d_out, int out_size, void* d_ws, size_t ws_size,
                              hipStream_t stream)
{
    const float* target = (const float*)d_in[0];
    const float* dk     = (const float*)d_in[1];
    float* out = (float*)d_out;

    uint8_t* wsb = (uint8_t*)d_ws;
    uint32_t* minmax = (uint32_t*)wsb;       // 2 x u32 at ws[0]
    uint8_t* fw = wsb + 256;                 // 4 MB u8 plane

    fw_kernel<<<NPIX / 4 / 256, 256, 0, stream>>>(target, fw, minmax);

    dim3 gridB(WW / TS, HH / TS);
    contour_kernel<<<gridB, 256, 0, stream>>>(fw, dk, out, minmax);

    norm_kernel<<<NPIX / 4 / 256, 256, 0, stream>>>(out, fw, minmax, out);
}